// Round 2
// baseline (454.475 us; speedup 1.0000x reference)
//
#include <hip/hip_runtime.h>
#include <hip/hip_bf16.h>

#define B_ 16
#define C_ 512
#define N_ 4096
#define EPSV 1e-6f

typedef __attribute__((ext_vector_type(8))) short bffrag;     // 8 bf16 (4 VGPR) MFMA A/B frag
typedef __attribute__((ext_vector_type(4))) float f32x4;      // MFMA C/D frag
typedef __attribute__((ext_vector_type(4))) unsigned short us4;
typedef __attribute__((ext_vector_type(8))) unsigned short us8;

__device__ __forceinline__ unsigned short f2bf(float f){
  unsigned u = __float_as_uint(f);
  u += 0x7fffu + ((u >> 16) & 1u);   // RNE; inputs are finite gaussians
  return (unsigned short)(u >> 16);
}

// async global->LDS, 16B per lane; lds base must be wave-uniform (lane0 dest),
// HW scatters lane i to base + i*16.
__device__ __forceinline__ void gload_lds16(const void* g, void* l){
  __builtin_amdgcn_global_load_lds(
      (__attribute__((address_space(1))) void*)g,
      (__attribute__((address_space(3))) void*)l, 16, 0, 0);
}

// ---------------------------------------------------------------------------
// K1: per-(b,n) reduction over channels. 1024 blocks; 4 c-strips x 64 lanes.
//     Also zeroes tvec (atomic target for k_prep).
// ---------------------------------------------------------------------------
__global__ __launch_bounds__(256) void k_reduce(const float* __restrict__ x,
    float* __restrict__ rnorm, float* __restrict__ vsum, float* __restrict__ rq,
    float* __restrict__ tvec){
  __shared__ float sd[2][4][64];
  const int t = threadIdx.x, lane = t & 63, strip = t >> 6;
  const int bid = blockIdx.x;
  const int b = bid >> 6, n0 = (bid & 63) * 64;
  if (bid < 32) tvec[bid * 256 + t] = 0.f;          // 32*256 = B_*C_
  const float* p = x + (size_t)b * C_ * N_ + n0 + lane;
  float s = 0.f, s2 = 0.f;
  #pragma unroll 8
  for (int c = strip * 128; c < strip * 128 + 128; ++c){
    float v = p[(size_t)c * N_];
    s += v; s2 += v * v;
  }
  sd[0][strip][lane] = s; sd[1][strip][lane] = s2;
  __syncthreads();
  if (t < 64){
    float ss = sd[0][0][t] + sd[0][1][t] + sd[0][2][t] + sd[0][3][t];
    float q2 = sd[1][0][t] + sd[1][1][t] + sd[1][2][t] + sd[1][3][t];
    float rn = 1.0f / sqrtf(q2);
    int idx = b * N_ + n0 + t;
    rnorm[idx] = rn; vsum[idx] = ss;
    rq[idx] = rn * (ss * rn + EPSV);
  }
}

// ---------------------------------------------------------------------------
// K1b: Qb = bf16(V * rnorm)  (64MB) + fused tailor dot t[c] += sum_n V*rq
//      8 consecutive n per thread; whole wave shares one row -> 1 atomic/wave.
// ---------------------------------------------------------------------------
__global__ __launch_bounds__(256) void k_prep(const float* __restrict__ x,
    const float* __restrict__ rnorm, const float* __restrict__ rq,
    unsigned short* __restrict__ Qb, float* __restrict__ tvec){
  const int idx = blockIdx.x * 256 + threadIdx.x;
  const size_t g = (size_t)idx * 8;
  const int row = (int)(g >> 12);        // b*C + c
  const int b = row >> 9;
  const int n = (int)(g & (N_ - 1));
  float4 v0 = *(const float4*)&x[g];
  float4 v1 = *(const float4*)&x[g + 4];
  const float* rnp = &rnorm[((size_t)b << 12) + n];
  const float* rqp = &rq[((size_t)b << 12) + n];
  float4 r0 = *(const float4*)rnp, r1 = *(const float4*)(rnp + 4);
  float4 q0 = *(const float4*)rqp, q1 = *(const float4*)(rqp + 4);
  us8 w;
  w[0] = f2bf(v0.x * r0.x); w[1] = f2bf(v0.y * r0.y);
  w[2] = f2bf(v0.z * r0.z); w[3] = f2bf(v0.w * r0.w);
  w[4] = f2bf(v1.x * r1.x); w[5] = f2bf(v1.y * r1.y);
  w[6] = f2bf(v1.z * r1.z); w[7] = f2bf(v1.w * r1.w);
  *(us8*)&Qb[g] = w;
  float p = v0.x*q0.x + v0.y*q0.y + v0.z*q0.z + v0.w*q0.w
          + v1.x*q1.x + v1.y*q1.y + v1.z*q1.z + v1.w*q1.w;
  #pragma unroll
  for (int m = 32; m; m >>= 1) p += __shfl_xor(p, m, 64);
  if ((threadIdx.x & 63) == 0) atomicAdd(&tvec[row], p);
}

// ---------------------------------------------------------------------------
// K2: GEMM1  matrix[b,c,m] = sum_n V[c,n]*Qn[m,n], split-K=2.
//     A: fp32 x -> convert -> LDS (padded).  B: Qb bf16 via global_load_lds.
// ---------------------------------------------------------------------------
__global__ __launch_bounds__(256) void k_gemm1(const float* __restrict__ x,
    const unsigned short* __restrict__ Qb, float* __restrict__ mpart){
  const int b    = blockIdx.y;
  const int tile = blockIdx.x & 15;
  const int ks   = blockIdx.x >> 4;
  const int ct = tile >> 2, mt = tile & 3;
  const int c0 = ct * 128, m0 = mt * 128;

  __shared__ unsigned short As[128 * 40];   // [c][k] padded
  __shared__ unsigned short Bs[128 * 32];   // [m][k] unpadded (async dest)

  const int t = threadIdx.x;
  const int lrow = t >> 3, lcg = t & 7;
  const int lane = t & 63, wave = t >> 6;
  const int wr = (wave & 1) * 64, wc = (wave >> 1) * 64;
  const int fr = lane & 15, quad = lane >> 4;
  const int brow = lane >> 2, bcol = (lane & 3) * 8;   // async geometry

  const float* Ag = x + (size_t)b * C_ * N_ + (size_t)c0 * N_;
  const unsigned short* Bg = Qb + (size_t)b * C_ * N_ + (size_t)m0 * N_;

  f32x4 acc[4][4];
  #pragma unroll
  for (int i = 0; i < 4; ++i)
    #pragma unroll
    for (int j = 0; j < 4; ++j) acc[i][j] = (f32x4){0.f, 0.f, 0.f, 0.f};

  for (int kc = 0; kc < 64; ++kc){
    const int k0 = ks * 2048 + kc * 32;
    float4 av[4];
    #pragma unroll
    for (int u = 0; u < 4; ++u)
      av[u] = *(const float4*)&Ag[(size_t)(lrow + u * 32) * N_ + k0 + lcg * 4];
    __syncthreads();            // prev iter's frag reads done
    #pragma unroll
    for (int q = 0; q < 2; ++q){   // B: 2x 1KB async per wave
      int sect = wave * 2 + q;
      gload_lds16(&Bg[(size_t)(sect * 16 + brow) * N_ + k0 + bcol],
                  &Bs[sect * 512]);
    }
    #pragma unroll
    for (int u = 0; u < 4; ++u){
      int row = lrow + u * 32;
      us4 aw; aw.x = f2bf(av[u].x); aw.y = f2bf(av[u].y);
              aw.z = f2bf(av[u].z); aw.w = f2bf(av[u].w);
      *(us4*)&As[row * 40 + lcg * 4] = aw;
    }
    __syncthreads();            // drains vmcnt (async B) + lgkm (A writes)
    bffrag af[4], bf[4];
    #pragma unroll
    for (int i = 0; i < 4; ++i)
      af[i] = *(const bffrag*)&As[(wr + i * 16 + fr) * 40 + quad * 8];
    #pragma unroll
    for (int j = 0; j < 4; ++j)
      bf[j] = *(const bffrag*)&Bs[(wc + j * 16 + fr) * 32 + quad * 8];
    #pragma unroll
    for (int i = 0; i < 4; ++i)
      #pragma unroll
      for (int j = 0; j < 4; ++j)
        acc[i][j] = __builtin_amdgcn_mfma_f32_16x16x32_bf16(af[i], bf[j], acc[i][j], 0, 0, 0);
  }

  float* op = mpart + ((size_t)(ks * 16 + b)) * (C_ * C_);
  #pragma unroll
  for (int i = 0; i < 4; ++i)
    #pragma unroll
    for (int r = 0; r < 4; ++r){
      int c = c0 + wr + i * 16 + quad * 4 + r;
      #pragma unroll
      for (int j = 0; j < 4; ++j)
        op[(size_t)c * C_ + m0 + wc + j * 16 + fr] = acc[i][j][r];
    }
}

// ---------------------------------------------------------------------------
// K2b: matrix = mpart[0]+mpart[1] -> bf16 Ab
// ---------------------------------------------------------------------------
__global__ __launch_bounds__(256) void k_sumcvt(const float* __restrict__ mpart,
                                                unsigned short* __restrict__ Ab){
  int idx = blockIdx.x * 256 + threadIdx.x;
  f32x4 a = *(const f32x4*)&mpart[(size_t)idx * 4];
  f32x4 c = *(const f32x4*)&mpart[(size_t)idx * 4 + (size_t)B_ * C_ * C_];
  us4 o;
  o.x = f2bf(a.x + c.x); o.y = f2bf(a.y + c.y);
  o.z = f2bf(a.z + c.z); o.w = f2bf(a.w + c.w);
  *(us4*)&Ab[(size_t)idx * 4] = o;
}

// ---------------------------------------------------------------------------
// K3: GEMM2 + epilogue.  A = Ab bf16 (async staging).  B = Qb bf16, in-LDS
//     transpose via scalar gathers.  out = x + gamma*((vsum + matrix@Qn)*tl)
// ---------------------------------------------------------------------------
__global__ __launch_bounds__(256) void k_gemm2(const float* __restrict__ x,
    const unsigned short* __restrict__ Ab, const unsigned short* __restrict__ Qb,
    const float* __restrict__ vsum, const float* __restrict__ tvec,
    const float* __restrict__ gamma, float* __restrict__ out){
  const int b  = blockIdx.y;
  const int ct = blockIdx.x >> 5;
  const int nt = blockIdx.x & 31;
  const int c0 = ct * 128, n0 = nt * 128;

  __shared__ unsigned short As[128 * 32];   // [c][m] unpadded (async dest)
  __shared__ unsigned short Bs[128 * 40];   // [n][m] padded (transpose dest)
  __shared__ float tl[128];

  const int t = threadIdx.x;
  if (t < 128) tl[t] = 1.0f / ((float)N_ + tvec[b * C_ + c0 + t]);
  const int lane = t & 63, wave = t >> 6;
  const int wr = (wave & 1) * 64;    // c
  const int wc = (wave >> 1) * 64;   // n
  const int fr = lane & 15, quad = lane >> 4;
  const int nloc = t & 127, mh = t >> 7;
  const int arow = lane >> 2, acol = (lane & 3) * 8;

  const unsigned short* Abb = Ab + (size_t)b * C_ * C_;
  const unsigned short* Qbb = Qb + (size_t)b * C_ * N_;
  const float* xb = x + (size_t)b * C_ * N_;

  f32x4 acc[4][4];
  #pragma unroll
  for (int i = 0; i < 4; ++i)
    #pragma unroll
    for (int j = 0; j < 4; ++j) acc[i][j] = (f32x4){0.f, 0.f, 0.f, 0.f};

  for (int kc = 0; kc < 16; ++kc){
    const int m0 = kc * 32;
    unsigned short bval[16];
    #pragma unroll
    for (int j = 0; j < 16; ++j)     // coalesced across lanes (n), strided rows (m)
      bval[j] = Qbb[(size_t)(m0 + mh * 16 + j) * N_ + n0 + nloc];
    __syncthreads();                 // prev frag reads done
    #pragma unroll
    for (int q = 0; q < 2; ++q){     // A async: 2x 1KB per wave
      int sect = wave * 2 + q;
      gload_lds16(&Abb[(size_t)(c0 + sect * 16 + arow) * C_ + m0 + acol],
                  &As[sect * 512]);
    }
    #pragma unroll
    for (int g2 = 0; g2 < 2; ++g2){
      us8 w;
      #pragma unroll
      for (int j = 0; j < 8; ++j) w[j] = bval[g2 * 8 + j];
      *(us8*)&Bs[nloc * 40 + mh * 16 + g2 * 8] = w;   // [n][k=m]
    }
    __syncthreads();
    bffrag af[4], bf[4];
    #pragma unroll
    for (int i = 0; i < 4; ++i)
      af[i] = *(const bffrag*)&As[(wr + i * 16 + fr) * 32 + quad * 8];
    #pragma unroll
    for (int j = 0; j < 4; ++j)
      bf[j] = *(const bffrag*)&Bs[(wc + j * 16 + fr) * 40 + quad * 8];
    #pragma unroll
    for (int i = 0; i < 4; ++i)
      #pragma unroll
      for (int j = 0; j < 4; ++j)
        acc[i][j] = __builtin_amdgcn_mfma_f32_16x16x32_bf16(af[i], bf[j], acc[i][j], 0, 0, 0);
  }

  const float g = gamma[0];
  const float* vs = vsum + (size_t)b * N_;
  float* ob = out + (size_t)b * C_ * N_;
  #pragma unroll
  for (int i = 0; i < 4; ++i)
    #pragma unroll
    for (int r = 0; r < 4; ++r){
      int c = c0 + wr + i * 16 + quad * 4 + r;
      float tll = tl[wr + i * 16 + quad * 4 + r];
      #pragma unroll
      for (int j = 0; j < 4; ++j){
        int n = n0 + wc + j * 16 + fr;
        float xv = xb[(size_t)c * N_ + n];
        ob[(size_t)c * N_ + n] = xv + g * ((vs[n] + acc[i][j][r]) * tll);
      }
    }
}

// ---------------------------------------------------------------------------
extern "C" void kernel_launch(void* const* d_in, const int* in_sizes, int n_in,
                              void* d_out, int out_size, void* d_ws, size_t ws_size,
                              hipStream_t stream){
  const float* x     = (const float*)d_in[0];
  const float* gamma = (const float*)d_in[1];
  float* out = (float*)d_out;
  char* ws = (char*)d_ws;

  // ws layout (bytes):
  unsigned short* Qb = (unsigned short*)(ws);            //  67,108,864
  float* mpart = (float*)(ws + 67108864);                //  33,554,432
  unsigned short* Ab = (unsigned short*)(ws + 100663296);//   8,388,608
  float* rnorm = (float*)(ws + 109051904);               //     262,144
  float* vsum  = (float*)(ws + 109314048);               //     262,144
  float* rq    = (float*)(ws + 109576192);               //     262,144
  float* tvec  = (float*)(ws + 109838336);               //      32,768
  // total 109,871,104 bytes

  k_reduce<<<dim3(B_ * N_ / 64), 256, 0, stream>>>(x, rnorm, vsum, rq, tvec);
  k_prep<<<dim3(B_ * C_ * N_ / 8 / 256), 256, 0, stream>>>(x, rnorm, rq, Qb, tvec);
  k_gemm1<<<dim3(32, B_), 256, 0, stream>>>(x, Qb, mpart);
  k_sumcvt<<<dim3(B_ * C_ * C_ / 4 / 256), 256, 0, stream>>>(mpart, Ab);
  k_gemm2<<<dim3(128, B_), 256, 0, stream>>>(x, Ab, Qb, vsum, tvec, gamma, out);
}

// Round 3
// 436.576 us; speedup vs baseline: 1.0410x; 1.0410x over previous
//
#include <hip/hip_runtime.h>
#include <hip/hip_bf16.h>

#define B_ 16
#define C_ 512
#define N_ 4096
#define EPSV 1e-6f

typedef __attribute__((ext_vector_type(8))) short bffrag;     // 8 bf16 (4 VGPR) MFMA A/B frag
typedef __attribute__((ext_vector_type(4))) float f32x4;      // MFMA C/D frag
typedef __attribute__((ext_vector_type(2))) unsigned short us2;
typedef __attribute__((ext_vector_type(4))) unsigned short us4;
typedef __attribute__((ext_vector_type(8))) unsigned short us8;

__device__ __forceinline__ unsigned short f2bf(float f){
  unsigned u = __float_as_uint(f);
  u += 0x7fffu + ((u >> 16) & 1u);   // RNE; inputs are finite gaussians
  return (unsigned short)(u >> 16);
}

// async global->LDS, 16B/lane; LDS base must be wave-uniform, HW scatters
// lane i to base + i*16.
__device__ __forceinline__ void gload_lds16(const void* g, void* l){
  __builtin_amdgcn_global_load_lds(
      (__attribute__((address_space(1))) void*)g,
      (__attribute__((address_space(3))) void*)l, 16, 0, 0);
}

// ---------------------------------------------------------------------------
// K1: fused reduce+prep. Block = (b, 64-n strip). Pass A: s, s2 per n.
// Pass B (L2/L3-hot re-read): Ph[c][n]=bf16(V*sqrt(rnorm)) + LDS-transposed
// Pt[n][c] (same values) + tpart[b][strip][c] = sum_n V*rq partials.
// ---------------------------------------------------------------------------
__global__ __launch_bounds__(256) void k_prep(const float* __restrict__ x,
    unsigned short* __restrict__ Ph, unsigned short* __restrict__ Pt,
    float* __restrict__ vsum, float* __restrict__ sqg,
    float* __restrict__ tpart){
  __shared__ float sdA[16][64], sdB[16][64];
  __shared__ float sql[64], rql[64];
  __shared__ unsigned short qtl[512 * 66];   // [c][nloc], stride 66 breaks banks

  const int t = threadIdx.x;
  const int b = blockIdx.x >> 6, strip = blockIdx.x & 63, n0 = strip * 64;
  const int rg = t >> 4, n4 = t & 15;
  const float* xs = x + (size_t)b * C_ * N_ + n0;

  // pass A: column sums
  float4 s4 = {0,0,0,0}, s24 = {0,0,0,0};
  #pragma unroll 8
  for (int k = 0; k < 32; ++k){
    float4 v = *(const float4*)&xs[(size_t)(k * 16 + rg) * N_ + n4 * 4];
    s4.x += v.x; s4.y += v.y; s4.z += v.z; s4.w += v.w;
    s24.x += v.x * v.x; s24.y += v.y * v.y;
    s24.z += v.z * v.z; s24.w += v.w * v.w;
  }
  *(float4*)&sdA[rg][n4 * 4] = s4;
  *(float4*)&sdB[rg][n4 * 4] = s24;
  __syncthreads();
  if (t < 64){
    float s = 0.f, s2 = 0.f;
    #pragma unroll
    for (int g2 = 0; g2 < 16; ++g2){ s += sdA[g2][t]; s2 += sdB[g2][t]; }
    float rn = 1.0f / sqrtf(s2);
    float sq = sqrtf(rn);
    vsum[b * N_ + n0 + t] = s;
    sqg [b * N_ + n0 + t] = sq;
    sql[t] = sq;
    rql[t] = rn * (s * rn + EPSV);
  }
  __syncthreads();

  // pass B
  float4 sq4 = *(float4*)&sql[n4 * 4];
  float4 rq4 = *(float4*)&rql[n4 * 4];
  unsigned short* Php = Ph + (size_t)b * C_ * N_ + n0;
  float* tpp = tpart + ((size_t)b * 64 + strip) * C_;
  #pragma unroll 4
  for (int k = 0; k < 32; ++k){
    int c = k * 16 + rg;
    float4 v = *(const float4*)&xs[(size_t)c * N_ + n4 * 4];
    us2 p0, p1;
    p0.x = f2bf(v.x * sq4.x); p0.y = f2bf(v.y * sq4.y);
    p1.x = f2bf(v.z * sq4.z); p1.y = f2bf(v.w * sq4.w);
    us4 ph; ph.x = p0.x; ph.y = p0.y; ph.z = p1.x; ph.w = p1.y;
    *(us4*)&Php[(size_t)c * N_ + n4 * 4] = ph;
    *(us2*)&qtl[c * 66 + n4 * 4]     = p0;   // 4B-aligned (66c+4n4 even)
    *(us2*)&qtl[c * 66 + n4 * 4 + 2] = p1;
    float tp = v.x * rq4.x + v.y * rq4.y + v.z * rq4.z + v.w * rq4.w;
    tp += __shfl_down(tp, 8, 16);
    tp += __shfl_down(tp, 4, 16);
    tp += __shfl_down(tp, 2, 16);
    tp += __shfl_down(tp, 1, 16);
    if (n4 == 0) tpp[c] = tp;
  }
  __syncthreads();

  // transposed output Pt[b][n][c]; lane reads c = lane+64j (bank stride 33%32=1)
  const int lane = t & 63, wave = t >> 6;
  unsigned short* Ptp = Pt + ((size_t)b * N_ + n0) * C_;
  for (int pr = wave; pr < 32; pr += 4){
    int r0 = pr * 2;
    unsigned short v0[8], v1[8];
    #pragma unroll
    for (int j = 0; j < 8; ++j){
      us2 w = *(const us2*)&qtl[(lane + 64 * j) * 66 + r0];
      v0[j] = w.x; v1[j] = w.y;
    }
    #pragma unroll
    for (int j = 0; j < 8; ++j){
      Ptp[(size_t)r0 * C_ + lane + 64 * j]       = v0[j];  // 128B/wave-inst
      Ptp[(size_t)(r0 + 1) * C_ + lane + 64 * j] = v1[j];
    }
  }
}

// ---------------------------------------------------------------------------
// K2: GEMM1  matrix = Ph @ Ph^T per batch, K=4096 single pass, bf16 out.
// 512 threads = 8 waves, each 64x32 (4x2 frags). 256 main blocks (1/CU)
// + 16 tail blocks reducing tpart -> tvec.
// ---------------------------------------------------------------------------
__global__ __launch_bounds__(512) void k_gemm1(const unsigned short* __restrict__ Ph,
    unsigned short* __restrict__ Ab, const float* __restrict__ tpart,
    float* __restrict__ tvec){
  const int bid = blockIdx.x;
  if (bid >= 256){                       // tail: tvec[b*C+c] = sum_strips tpart
    int i = (bid - 256) * 512 + threadIdx.x;   // 16*512 = 8192 = B_*C_
    const float* tp = tpart + (size_t)(i >> 9) * 64 * C_ + (i & 511);
    float s = 0.f;
    #pragma unroll 8
    for (int k = 0; k < 64; ++k) s += tp[(size_t)k * C_];
    tvec[i] = s;
    return;
  }
  const int b = bid >> 4, tile = bid & 15;
  const int c0 = (tile >> 2) * 128, m0 = (tile & 3) * 128;
  __shared__ unsigned short As[4096], Bs[4096];   // 8KB + 8KB, async dests

  const int t = threadIdx.x, lane = t & 63, wave = t >> 6;
  const int wr = (wave & 1) * 64, wc = (wave >> 1) * 32;
  const int fr = lane & 15, quad = lane >> 4;

  const unsigned short* Agl =
      Ph + (size_t)(b * C_ + c0 + wave * 16 + (lane >> 2)) * N_ + (lane & 3) * 8;
  const unsigned short* Bgl =
      Ph + (size_t)(b * C_ + m0 + wave * 16 + (lane >> 2)) * N_ + (lane & 3) * 8;

  f32x4 acc[4][2];
  #pragma unroll
  for (int i = 0; i < 4; ++i)
    #pragma unroll
    for (int j = 0; j < 2; ++j) acc[i][j] = (f32x4){0.f, 0.f, 0.f, 0.f};

  for (int kc = 0; kc < 128; ++kc){
    __syncthreads();                       // prev frag reads done
    gload_lds16(Agl + kc * 32, &As[wave * 512]);
    gload_lds16(Bgl + kc * 32, &Bs[wave * 512]);
    __syncthreads();                       // vmcnt drained
    bffrag af[4], bf[2];
    #pragma unroll
    for (int i = 0; i < 4; ++i)
      af[i] = *(const bffrag*)&As[(wr + i * 16 + fr) * 32 + quad * 8];
    #pragma unroll
    for (int j = 0; j < 2; ++j)
      bf[j] = *(const bffrag*)&Bs[(wc + j * 16 + fr) * 32 + quad * 8];
    #pragma unroll
    for (int i = 0; i < 4; ++i)
      #pragma unroll
      for (int j = 0; j < 2; ++j)
        acc[i][j] = __builtin_amdgcn_mfma_f32_16x16x32_bf16(af[i], bf[j], acc[i][j], 0, 0, 0);
  }

  unsigned short* op = Ab + (size_t)b * C_ * C_;
  #pragma unroll
  for (int i = 0; i < 4; ++i)
    #pragma unroll
    for (int r = 0; r < 4; ++r){
      int c = c0 + wr + i * 16 + quad * 4 + r;
      #pragma unroll
      for (int j = 0; j < 2; ++j)
        op[(size_t)c * C_ + m0 + wc + j * 16 + fr] = f2bf(acc[i][j][r]);
    }
}

// ---------------------------------------------------------------------------
// K3: GEMM2 + epilogue. A = Ab[c][m] bf16 async, B = Pt[n][m] bf16 async.
// out[c,n] = x + gamma*((vsum[n] + s[n]*acc)*tl[c]); float4 epilogue via
// LDS bounce (smem unions As/Bs with the fp32 acc tile).
// ---------------------------------------------------------------------------
__global__ __launch_bounds__(256) void k_gemm2(const float* __restrict__ x,
    const unsigned short* __restrict__ Ab, const unsigned short* __restrict__ Pt,
    const float* __restrict__ vsum, const float* __restrict__ sqg,
    const float* __restrict__ tvec, const float* __restrict__ gamma,
    float* __restrict__ out){
  const int b  = blockIdx.y;
  const int c0 = (blockIdx.x >> 5) * 128, n0 = (blockIdx.x & 31) * 128;

  __shared__ __align__(16) char smem[128 * 132 * 4];   // 67.6KB union
  unsigned short* As = (unsigned short*)smem;          // 8KB
  unsigned short* Bs = As + 4096;                      // 8KB
  float (*eps)[132] = (float(*)[132])smem;             // epilogue fp32 tile
  __shared__ float tl[128];

  const int t = threadIdx.x, lane = t & 63, wave = t >> 6;
  if (t < 128) tl[t] = 1.0f / ((float)N_ + tvec[b * C_ + c0 + t]);
  const int wr = (wave & 1) * 64, wc = (wave >> 1) * 64;
  const int fr = lane & 15, quad = lane >> 4;

  const unsigned short* Agl = Ab + (size_t)b * C_ * C_
      + (size_t)(c0 + wave * 32 + (lane >> 2)) * C_ + (lane & 3) * 8;
  const unsigned short* Bgl = Pt + ((size_t)b * N_ + n0 + wave * 32 + (lane >> 2)) * C_
      + (lane & 3) * 8;

  f32x4 acc[4][4];
  #pragma unroll
  for (int i = 0; i < 4; ++i)
    #pragma unroll
    for (int j = 0; j < 4; ++j) acc[i][j] = (f32x4){0.f, 0.f, 0.f, 0.f};

  for (int kc = 0; kc < 16; ++kc){
    __syncthreads();
    gload_lds16(Agl + kc * 32,           &As[(wave * 2) * 512]);
    gload_lds16(Agl + 16 * C_ + kc * 32, &As[(wave * 2 + 1) * 512]);
    gload_lds16(Bgl + kc * 32,           &Bs[(wave * 2) * 512]);
    gload_lds16(Bgl + 16 * C_ + kc * 32, &Bs[(wave * 2 + 1) * 512]);
    __syncthreads();
    bffrag af[4], bf[4];
    #pragma unroll
    for (int i = 0; i < 4; ++i)
      af[i] = *(const bffrag*)&As[(wr + i * 16 + fr) * 32 + quad * 8];
    #pragma unroll
    for (int j = 0; j < 4; ++j)
      bf[j] = *(const bffrag*)&Bs[(wc + j * 16 + fr) * 32 + quad * 8];
    #pragma unroll
    for (int i = 0; i < 4; ++i)
      #pragma unroll
      for (int j = 0; j < 4; ++j)
        acc[i][j] = __builtin_amdgcn_mfma_f32_16x16x32_bf16(af[i], bf[j], acc[i][j], 0, 0, 0);
  }

  // epilogue: dump acc to LDS, re-read as float4 rows, fused RMW
  __syncthreads();                       // done with As/Bs
  #pragma unroll
  for (int i = 0; i < 4; ++i)
    #pragma unroll
    for (int r = 0; r < 4; ++r)
      #pragma unroll
      for (int j = 0; j < 4; ++j)
        eps[wr + i * 16 + quad * 4 + r][wc + j * 16 + fr] = acc[i][j][r];
  __syncthreads();

  const float g = gamma[0];
  const float* vs = vsum + (size_t)b * N_ + n0;
  const float* sq = sqg  + (size_t)b * N_ + n0;
  const float* xb  = x   + (size_t)b * C_ * N_;
  float* ob        = out + (size_t)b * C_ * N_;
  #pragma unroll
  for (int p = 0; p < 16; ++p){
    int row = p * 8 + (t >> 5), colb = (t & 31) * 4;
    int c = c0 + row, n = n0 + colb;
    float4 a   = *(float4*)&eps[row][colb];
    float4 xv  = *(const float4*)&xb[(size_t)c * N_ + n];
    float4 v4  = *(const float4*)&vs[colb];
    float4 s4  = *(const float4*)&sq[colb];
    float tlc = tl[row];
    float4 o;
    o.x = xv.x + g * ((v4.x + s4.x * a.x) * tlc);
    o.y = xv.y + g * ((v4.y + s4.y * a.y) * tlc);
    o.z = xv.z + g * ((v4.z + s4.z * a.z) * tlc);
    o.w = xv.w + g * ((v4.w + s4.w * a.w) * tlc);
    *(float4*)&ob[(size_t)c * N_ + n] = o;
  }
}

// ---------------------------------------------------------------------------
extern "C" void kernel_launch(void* const* d_in, const int* in_sizes, int n_in,
                              void* d_out, int out_size, void* d_ws, size_t ws_size,
                              hipStream_t stream){
  const float* x     = (const float*)d_in[0];
  const float* gamma = (const float*)d_in[1];
  float* out = (float*)d_out;
  char* ws = (char*)d_ws;

  // ws layout (bytes):
  unsigned short* Ph = (unsigned short*)(ws);              //  67,108,864
  unsigned short* Pt = (unsigned short*)(ws + 67108864);   //  67,108,864
  unsigned short* Ab = (unsigned short*)(ws + 134217728);  //   8,388,608
  float* tpart = (float*)(ws + 142606336);                 //   2,097,152
  float* vsum  = (float*)(ws + 144703488);                 //     262,144
  float* sqg   = (float*)(ws + 144965632);                 //     262,144
  float* tvec  = (float*)(ws + 145227776);                 //      32,768
  // total 145,260,544 bytes

  k_prep<<<dim3(B_ * 64), 256, 0, stream>>>(x, Ph, Pt, vsum, sqg, tpart);
  k_gemm1<<<dim3(272), 512, 0, stream>>>(Ph, Ab, tpart, tvec);
  k_gemm2<<<dim3(128, B_), 256, 0, stream>>>(x, Ab, Pt, vsum, sqg, tvec, gamma, out);
}